// Round 13
// baseline (1318.697 us; speedup 1.0000x reference)
//
#include <hip/hip_runtime.h>
#include <hip/hip_bf16.h>

#define BB 4
#define SS 2048
#define HH 2048
#define KK 1024
#define LL 2
#define NHH 16
#define FFF 4096
#define DD 128

typedef __attribute__((ext_vector_type(8))) short s8v;
typedef __attribute__((ext_vector_type(4))) short s4v;
typedef __attribute__((ext_vector_type(4))) float f4v;

__device__ __forceinline__ short f2bf(float f) {
  unsigned u = __builtin_bit_cast(unsigned, f);
  u += 0x7fffu + ((u >> 16) & 1u);   // RNE
  return (short)(u >> 16);
}
__device__ __forceinline__ float bf2f(short s) {
  unsigned u = ((unsigned)(unsigned short)s) << 16;
  return __builtin_bit_cast(float, u);
}
__device__ __forceinline__ f4v mfma16(s8v a, s8v b, f4v c) {
  asm("v_mfma_f32_16x16x32_bf16 %0, %1, %2, %0" : "+v"(c) : "v"(a), "v"(b));
  return c;
}
// volatile variant: pinned inside its phase (between barriers) for the
// phase-split GEMM schedule
__device__ __forceinline__ f4v mfma16v(s8v a, s8v b, f4v c) {
  asm volatile("v_mfma_f32_16x16x32_bf16 %0, %1, %2, %0" : "+v"(c) : "v"(a), "v"(b));
  return c;
}
__device__ __forceinline__ void gload_lds16(const void* g, void* l) {
  __builtin_amdgcn_global_load_lds(
      (__attribute__((address_space(1))) void*)g,
      (__attribute__((address_space(3))) void*)l, 16, 0, 0);
}
// Counted-vmcnt barrier: drains expcnt+lgkm fully (expcnt tracks the LDS-write
// half of global_load_lds on gfx950) leaving newest prefetch stage in flight.
template <int N>
__device__ __forceinline__ void barrier_cnt() {
  if constexpr (N == 3)
    asm volatile("s_waitcnt vmcnt(3) expcnt(0) lgkmcnt(0)" ::: "memory");
  else if constexpr (N == 4)
    asm volatile("s_waitcnt vmcnt(4) expcnt(0) lgkmcnt(0)" ::: "memory");
  else
    asm volatile("s_waitcnt vmcnt(0) expcnt(0) lgkmcnt(0)" ::: "memory");
  __builtin_amdgcn_s_barrier();
  asm volatile("" ::: "memory");
}
// raw scheduling barrier (no drain) -- no LDS buffer handoff occurs here:
// staging always targets buffer cur+2, reads target cur.
__device__ __forceinline__ void midbar() {
  asm volatile("" ::: "memory");
  __builtin_amdgcn_s_barrier();
  asm volatile("" ::: "memory");
}
__device__ __forceinline__ void lgkm0() {
  asm volatile("s_waitcnt lgkmcnt(0)" ::: "memory");
  __builtin_amdgcn_sched_barrier(0);   // rule #18
}
__device__ __forceinline__ void prio1() { __builtin_amdgcn_s_setprio(1); }
__device__ __forceinline__ void prio0() { __builtin_amdgcn_s_setprio(0); }

// ---- weight transpose+convert: W[Kd][N] f32 -> Wt[map(n)][Kd] bf16 ----
// rowmap 0: identity. 1: gate-interleave  n -> 2*(n&~15) + (n&15)
//          2: up-interleave    n -> 2*(n&~15) + 16 + (n&15)
__global__ __launch_bounds__(256) void wconv(const float* __restrict__ W,
                                             short* __restrict__ Wt,
                                             int Kd, int N, int rowmap) {
  __shared__ short tile[64][65];
  int n0 = blockIdx.x * 64, k0 = blockIdx.y * 64;
  int t = threadIdx.x;
#pragma unroll
  for (int i = 0; i < 16; ++i) {
    int lin = i * 256 + t;
    int r = lin >> 6, c = lin & 63;
    tile[c][r] = f2bf(W[(size_t)(k0 + r) * N + n0 + c]);
  }
  __syncthreads();
#pragma unroll
  for (int i = 0; i < 16; ++i) {
    int lin = i * 256 + t;
    int r = lin >> 6, c = lin & 63;
    int n = n0 + r;
    int nf = (rowmap == 0) ? n : (((n & ~15) << 1) + (n & 15) + (rowmap == 2 ? 16 : 0));
    Wt[(size_t)nf * Kd + k0 + c] = tile[r][c];
  }
}

// ---- gather selected rows; produce cur_f32, cur_bf16, mem_bf16 ----
__global__ __launch_bounds__(256) void gather_rows(
    const float* __restrict__ x, const float* __restrict__ prev,
    const int* __restrict__ idx, float* __restrict__ cur_f,
    short* __restrict__ cur_b, short* __restrict__ mem_b) {
  int r = blockIdx.x;
  int b = r >> 10, kk = r & (KK - 1);
  int src = idx[b * KK + kk];
  const float4* xs = (const float4*)(x + ((size_t)b * SS + src) * HH);
  const float4* ps = (const float4*)(prev + ((size_t)b * SS + src) * HH);
  float4* cf = (float4*)(cur_f + (size_t)r * HH);
  s4v* cb = (s4v*)(cur_b + (size_t)r * HH);
  s4v* mb = (s4v*)(mem_b + (size_t)r * HH);
  int t = threadIdx.x;
#pragma unroll
  for (int i = 0; i < 2; ++i) {
    int c = t + i * 256;
    float4 xv = xs[c], pv = ps[c];
    cf[c] = xv;
    s4v cv, mv;
    cv[0] = f2bf(xv.x); cv[1] = f2bf(xv.y); cv[2] = f2bf(xv.z); cv[3] = f2bf(xv.w);
    mv[0] = f2bf(pv.x); mv[1] = f2bf(pv.y); mv[2] = f2bf(pv.z); mv[3] = f2bf(pv.w);
    cb[c] = cv; mb[c] = mv;
  }
}

// ==== g8p: 8-wave 128x256, waves 64x64; 3-buffer counted-vmcnt + T2 ====
// 2-phase K-step (m201-style): {reads+stage -> bar -> lgkm0 -> prio1 ->
// 8 MFMA -> prio0 -> bar} x2; tile-end barrier carries counted vmcnt.
// EPI: 0=bf16, 1=f32 +=, 2=V-transpose bf16
template <int EPI>
__global__ __launch_bounds__(512, 2) void g8p(
    const short* __restrict__ A, const short* __restrict__ Bt,
    float* __restrict__ Cf, short* __restrict__ Cb,
    int M, int N, int Kd) {
  __shared__ __align__(16) short smem[3 * 12288];
  const int t = threadIdx.x;
  const int w = t >> 6, l = t & 63;
  const int wr = w >> 2, wc = w & 3;            // 2(M) x 4(N) waves
  const int l15 = l & 15, lh = l >> 4;
  const int koffs = (lh ^ ((l15 >> 1) & 3)) * 8;

  const int gx = gridDim.x, gy = gridDim.y;
  const int nwg = gx * gy;
  const int bid = blockIdx.y * gx + blockIdx.x;
  const int wg = (bid & 7) * (nwg >> 3) + (bid >> 3);
  const int by = wg & (gy - 1);
  const int bx = wg / gy;
  const int rowBase = by * 128, colBase = bx * 256;

  const int ar = t >> 2;
  const int ac = ((t & 3) ^ ((t >> 3) & 3)) * 8;
  const short* gA = A + (size_t)(rowBase + ar) * Kd + ac;
  const short* gB0 = Bt + (size_t)(colBase + ar) * Kd + ac;
  const short* gB1 = gB0 + (size_t)128 * Kd;
  const int lA = t * 8;
  const int lB = 4096 + t * 8;

  f4v acc[4][4];
#pragma unroll
  for (int i = 0; i < 4; ++i)
#pragma unroll
    for (int j = 0; j < 4; ++j) acc[i][j] = (f4v){0.f, 0.f, 0.f, 0.f};

  const int NT = Kd >> 5;
  {   // prologue: stage tiles 0,1 fully
    gload_lds16(gA, smem + lA);
    gload_lds16(gB0, smem + lB);
    gload_lds16(gB1, smem + lB + 4096);
    gload_lds16(gA + 32, smem + 12288 + lA);
    gload_lds16(gB0 + 32, smem + 12288 + lB);
    gload_lds16(gB1 + 32, smem + 12288 + lB + 4096);
  }
  barrier_cnt<3>();

  int cur = 0;
  for (int kt = 0; kt < NT; ++kt) {
    const short* sb = smem + cur * 12288;
    const bool more = (kt + 2 < NT);
    int nb = cur + 2; if (nb >= 3) nb -= 3;
    short* nbase = smem + nb * 12288;
    const int k0 = (kt + 2) * 32;
    s8v af[4], bf[4];
    // ---- P1: A frags + B lo; stage A of kt+2 ----
#pragma unroll
    for (int mt = 0; mt < 4; ++mt)
      af[mt] = *(const s8v*)(sb + (wr * 64 + mt * 16 + l15) * 32 + koffs);
#pragma unroll
    for (int nt = 0; nt < 2; ++nt)
      bf[nt] = *(const s8v*)(sb + 4096 + (wc * 64 + nt * 16 + l15) * 32 + koffs);
    if (more) gload_lds16(gA + k0, nbase + lA);
    midbar();
    lgkm0();
    prio1();
#pragma unroll
    for (int mt = 0; mt < 4; ++mt)
#pragma unroll
      for (int nt = 0; nt < 2; ++nt)
        acc[mt][nt] = mfma16v(af[mt], bf[nt], acc[mt][nt]);
    prio0();
    midbar();
    // ---- P2: B hi; stage B of kt+2 ----
#pragma unroll
    for (int nt = 2; nt < 4; ++nt)
      bf[nt] = *(const s8v*)(sb + 4096 + (wc * 64 + nt * 16 + l15) * 32 + koffs);
    if (more) {
      gload_lds16(gB0 + k0, nbase + lB);
      gload_lds16(gB1 + k0, nbase + lB + 4096);
    }
    midbar();
    lgkm0();
    prio1();
#pragma unroll
    for (int mt = 0; mt < 4; ++mt)
#pragma unroll
      for (int nt = 2; nt < 4; ++nt)
        acc[mt][nt] = mfma16v(af[mt], bf[nt], acc[mt][nt]);
    prio0();
    if (more) barrier_cnt<3>(); else barrier_cnt<0>();
    cur = (cur + 1 == 3) ? 0 : cur + 1;
  }

#pragma unroll
  for (int mt = 0; mt < 4; ++mt) {
#pragma unroll
    for (int nt = 0; nt < 4; ++nt) {
#pragma unroll
      for (int rr = 0; rr < 4; ++rr) {
        int row = rowBase + wr * 64 + mt * 16 + lh * 4 + rr;
        int col = colBase + wc * 64 + nt * 16 + l15;
        float v = acc[mt][nt][rr];
        if constexpr (EPI == 0) {
          Cb[(size_t)row * N + col] = f2bf(v);
        } else if constexpr (EPI == 1) {
          Cf[(size_t)row * N + col] += v;
        } else if constexpr (EPI == 2) {
          int b = row >> 10, ktok = row & (KK - 1);
          int h = col >> 7, dd = col & (DD - 1);
          Cb[(((size_t)(b * NHH + h)) * DD + dd) * KK + ktok] = f2bf(v);
        }
      }
    }
  }
}

// ==== g256: 256x256 tile, 8 waves of 64x128; 2-phase K-step ====
// EPI 5: fused K|V; EPI 7: interleaved gate|up with in-register SwiGLU
template <int EPI>
__global__ __launch_bounds__(512, 2) void g256(
    const short* __restrict__ A, const short* __restrict__ Bt,
    short* __restrict__ Cb, short* __restrict__ Cb2, int M, int N, int Kd) {
  __shared__ __align__(16) short smem[3 * 16384];
  const int t = threadIdx.x;
  const int w = t >> 6, l = t & 63;
  const int wr = w >> 1, wc = w & 1;            // 4(M) x 2(N) waves
  const int l15 = l & 15, lh = l >> 4;
  const int koffs = (lh ^ ((l15 >> 1) & 3)) * 8;

  const int gx = gridDim.x, gy = gridDim.y;
  const int nwg = gx * gy;
  const int bid = blockIdx.y * gx + blockIdx.x;
  const int wg = (bid & 7) * (nwg >> 3) + (bid >> 3);
  const int by = wg & (gy - 1);
  const int bx = wg / gy;
  const int rowBase = by * 256, colBase = bx * 256;

  const int ar = t >> 2;
  const int ac = ((t & 3) ^ ((t >> 3) & 3)) * 8;
  const short* gA = A + (size_t)(rowBase + ar) * Kd + ac;
  const short* gB = Bt + (size_t)(colBase + ar) * Kd + ac;
  const int lA = t * 8;
  const int lB = 8192 + t * 8;

  f4v acc[4][8];
#pragma unroll
  for (int i = 0; i < 4; ++i)
#pragma unroll
    for (int j = 0; j < 8; ++j) acc[i][j] = (f4v){0.f, 0.f, 0.f, 0.f};

  const int NT = Kd >> 5;
  {   // prologue
#pragma unroll
    for (int b2 = 0; b2 < 2; ++b2) {
      short* base = smem + b2 * 16384;
      gload_lds16(gA + b2 * 32, base + lA);
      gload_lds16(gA + b2 * 32 + (size_t)128 * Kd, base + lA + 4096);
      gload_lds16(gB + b2 * 32, base + lB);
      gload_lds16(gB + b2 * 32 + (size_t)128 * Kd, base + lB + 4096);
    }
  }
  barrier_cnt<4>();

  int cur = 0;
  for (int kt = 0; kt < NT; ++kt) {
    const short* sb = smem + cur * 16384;
    const bool more = (kt + 2 < NT);
    int nb = cur + 2; if (nb >= 3) nb -= 3;
    short* nbase = smem + nb * 16384;
    const int k0 = (kt + 2) * 32;
    s8v af[4], bf[8];
    // ---- P1: A frags + B lo; stage A of kt+2 ----
#pragma unroll
    for (int mt = 0; mt < 4; ++mt)
      af[mt] = *(const s8v*)(sb + (wr * 64 + mt * 16 + l15) * 32 + koffs);
#pragma unroll
    for (int nt = 0; nt < 4; ++nt)
      bf[nt] = *(const s8v*)(sb + 8192 + (wc * 128 + nt * 16 + l15) * 32 + koffs);
    if (more) {
      gload_lds16(gA + k0, nbase + lA);
      gload_lds16(gA + k0 + (size_t)128 * Kd, nbase + lA + 4096);
    }
    midbar();
    lgkm0();
    prio1();
#pragma unroll
    for (int mt = 0; mt < 4; ++mt)
#pragma unroll
      for (int nt = 0; nt < 4; ++nt)
        acc[mt][nt] = mfma16v(af[mt], bf[nt], acc[mt][nt]);
    prio0();
    midbar();
    // ---- P2: B hi; stage B of kt+2 ----
#pragma unroll
    for (int nt = 4; nt < 8; ++nt)
      bf[nt] = *(const s8v*)(sb + 8192 + (wc * 128 + nt * 16 + l15) * 32 + koffs);
    if (more) {
      gload_lds16(gB + k0, nbase + lB);
      gload_lds16(gB + k0 + (size_t)128 * Kd, nbase + lB + 4096);
    }
    midbar();
    lgkm0();
    prio1();
#pragma unroll
    for (int mt = 0; mt < 4; ++mt)
#pragma unroll
      for (int nt = 4; nt < 8; ++nt)
        acc[mt][nt] = mfma16v(af[mt], bf[nt], acc[mt][nt]);
    prio0();
    if (more) barrier_cnt<4>(); else barrier_cnt<0>();
    cur = (cur + 1 == 3) ? 0 : cur + 1;
  }

#pragma unroll
  for (int mt = 0; mt < 4; ++mt) {
    if constexpr (EPI == 5) {
#pragma unroll
      for (int nt = 0; nt < 8; ++nt) {
#pragma unroll
        for (int rr = 0; rr < 4; ++rr) {
          int row = rowBase + wr * 64 + mt * 16 + lh * 4 + rr;
          int col = colBase + wc * 128 + nt * 16 + l15;
          float v = acc[mt][nt][rr];
          if (col < HH) {
            Cb[(size_t)row * HH + col] = f2bf(v);
          } else {
            int vcol = col - HH;
            int b = row >> 10, ktok = row & (KK - 1);
            int h = vcol >> 7, dd = vcol & (DD - 1);
            Cb2[(((size_t)(b * NHH + h)) * DD + dd) * KK + ktok] = f2bf(v);
          }
        }
      }
    } else {   // EPI 7: in-register SwiGLU; nt even = gate, nt+1 = up (same j)
#pragma unroll
      for (int nt = 0; nt < 8; nt += 2) {
#pragma unroll
        for (int rr = 0; rr < 4; ++rr) {
          int row = rowBase + wr * 64 + mt * 16 + lh * 4 + rr;
          int c = colBase + wc * 128 + nt * 16 + l15;
          int j = ((c >> 5) << 4) | (c & 15);
          float g = acc[mt][nt][rr];
          float u = acc[mt][nt + 1][rr];
          float h = (g / (1.f + __expf(-g))) * u;
          Cb[(size_t)row * FFF + j] = f2bf(h);
        }
      }
    }
  }
}

// ---- fused attention: log2-space softmax with native v_exp ----
__device__ __forceinline__ float exp2fast(float x) {
  float r;
  asm("v_exp_f32 %0, %1\n\ts_nop 0" : "=v"(r) : "v"(x));
  return r;
}
__global__ __launch_bounds__(256, 2) void attn_fwd(
    const short* __restrict__ qb, const short* __restrict__ kb,
    const short* __restrict__ vT, short* __restrict__ ob) {
  __shared__ __align__(16) short Kl[64 * 136];
  __shared__ __align__(16) short Vl[128 * 72];
  __shared__ __align__(16) short Pl[64 * 72];
  int b = blockIdx.z, h = blockIdx.y, qt = blockIdx.x;
  int t = threadIdx.x, w = t >> 6, l = t & 63, l15 = l & 15, lh = l >> 4;
  const float LOG2E = 1.4426950408889634f;
  float slope2 = exp2f(-0.5f * (float)(h + 1)) * LOG2E;
  const float c1 = 0.08838834764831845f * LOG2E;

  s8v qf[4];
  int qrowA = qt * 64 + w * 16 + l15;
  const short* qptr = qb + ((size_t)(b * KK + qrowA)) * HH + h * DD + lh * 8;
#pragma unroll
  for (int ks = 0; ks < 4; ++ks) qf[ks] = *(const s8v*)(qptr + ks * 32);

  f4v oacc[8];
#pragma unroll
  for (int i = 0; i < 8; ++i) oacc[i] = (f4v){0.f, 0.f, 0.f, 0.f};
  float m[4], sden[4];
#pragma unroll
  for (int r = 0; r < 4; ++r) { m[r] = -1e30f; sden[r] = 0.f; }
  int qpos_base = qt * 64 + w * 16 + lh * 4;

  for (int kt = 0; kt < KK / 64; ++kt) {
    {
      int rr = t >> 4, cc = (t & 15) * 8;
#pragma unroll
      for (int it = 0; it < 4; ++it) {
        int krow = it * 16 + rr;
        s8v g = *(const s8v*)(kb + ((size_t)(b * KK + kt * 64 + krow)) * HH + h * DD + cc);
        *(s8v*)&Kl[krow * 136 + cc] = g;
      }
      int dr = t >> 3, c2 = (t & 7) * 8;
#pragma unroll
      for (int it = 0; it < 4; ++it) {
        int drow = it * 32 + dr;
        s8v g = *(const s8v*)(vT + (((size_t)(b * NHH + h)) * DD + drow) * KK + kt * 64 + c2);
        *(s8v*)&Vl[drow * 72 + c2] = g;
      }
    }
    __syncthreads();

    f4v sacc[4];
#pragma unroll
    for (int ct = 0; ct < 4; ++ct) sacc[ct] = (f4v){0.f, 0.f, 0.f, 0.f};
#pragma unroll
    for (int ct = 0; ct < 4; ++ct)
#pragma unroll
      for (int ks = 0; ks < 4; ++ks) {
        s8v kf = *(const s8v*)&Kl[(ct * 16 + l15) * 136 + ks * 32 + lh * 8];
        sacc[ct] = mfma16(qf[ks], kf, sacc[ct]);
      }

#pragma unroll
    for (int r = 0; r < 4; ++r) {
      int qpos = qpos_base + r;
      float mx = -1e30f;
#pragma unroll
      for (int ct = 0; ct < 4; ++ct) {
        int kpos = kt * 64 + ct * 16 + l15;
        float sv = sacc[ct][r] * c1 - slope2 * fabsf((float)(qpos - kpos));
        sacc[ct][r] = sv;
        mx = fmaxf(mx, sv);
      }
      mx = fmaxf(mx, __shfl_xor(mx, 1));
      mx = fmaxf(mx, __shfl_xor(mx, 2));
      mx = fmaxf(mx, __shfl_xor(mx, 4));
      mx = fmaxf(mx, __shfl_xor(mx, 8));
      float mn = fmaxf(m[r], mx);
      float corr = exp2fast(m[r] - mn);
      m[r] = mn;
      float ps = 0.f;
#pragma unroll
      for (int ct = 0; ct < 4; ++ct) {
        float p = exp2fast(sacc[ct][r] - mn);
        sacc[ct][r] = p;
        ps += p;
      }
      ps += __shfl_xor(ps, 1); ps += __shfl_xor(ps, 2);
      ps += __shfl_xor(ps, 4); ps += __shfl_xor(ps, 8);
      sden[r] = sden[r] * corr + ps;
#pragma unroll
      for (int dt = 0; dt < 8; ++dt) oacc[dt][r] *= corr;
#pragma unroll
      for (int ct = 0; ct < 4; ++ct)
        Pl[(w * 16 + lh * 4 + r) * 72 + ct * 16 + l15] = f2bf(sacc[ct][r]);
    }

#pragma unroll
    for (int ks2 = 0; ks2 < 2; ++ks2) {
      s8v pa = *(const s8v*)&Pl[(w * 16 + l15) * 72 + ks2 * 32 + lh * 8];
#pragma unroll
      for (int dt = 0; dt < 8; ++dt) {
        s8v vf = *(const s8v*)&Vl[(dt * 16 + l15) * 72 + ks2 * 32 + lh * 8];
        oacc[dt] = mfma16(pa, vf, oacc[dt]);
      }
    }
    __syncthreads();
  }

#pragma unroll
  for (int dt = 0; dt < 8; ++dt)
#pragma unroll
    for (int r = 0; r < 4; ++r) {
      int qpos = qpos_base + r;
      int dd = dt * 16 + l15;
      ob[((size_t)(b * KK + qpos)) * HH + h * DD + dd] = f2bf(oacc[dt][r] / sden[r]);
    }
}

// ---- LayerNorm over rows of HH; writes bf16 (+ optional f32 in-place) ----
__global__ __launch_bounds__(256) void ln_rows(const float* in,
    const float* __restrict__ gma, const float* __restrict__ bta,
    short* __restrict__ outb, float* outf) {
  __shared__ float red[2][4];
  int r = blockIdx.x, t = threadIdx.x;
  const float4* x4 = (const float4*)(in + (size_t)r * HH);
  float4 va = x4[t], vb = x4[t + 256];
  float sum = va.x + va.y + va.z + va.w + vb.x + vb.y + vb.z + vb.w;
  float sq = va.x * va.x + va.y * va.y + va.z * va.z + va.w * va.w +
             vb.x * vb.x + vb.y * vb.y + vb.z * vb.z + vb.w * vb.w;
#pragma unroll
  for (int off = 32; off; off >>= 1) {
    sum += __shfl_down(sum, off);
    sq += __shfl_down(sq, off);
  }
  int w = t >> 6;
  if ((t & 63) == 0) { red[0][w] = sum; red[1][w] = sq; }
  __syncthreads();
  sum = red[0][0] + red[0][1] + red[0][2] + red[0][3];
  sq = red[1][0] + red[1][1] + red[1][2] + red[1][3];
  float mu = sum * (1.f / HH);
  float rs = rsqrtf(sq * (1.f / HH) - mu * mu + 1e-5f);
  const float4* g4 = (const float4*)gma;
  const float4* b4 = (const float4*)bta;
  s4v* ob = (s4v*)(outb + (size_t)r * HH);
  float4* of = (float4*)(outf ? outf + (size_t)r * HH : nullptr);
#pragma unroll
  for (int i = 0; i < 2; ++i) {
    int c = t + i * 256;
    float4 v = (i == 0) ? va : vb;
    float4 g = g4[c], bb = b4[c];
    float4 nv;
    nv.x = (v.x - mu) * rs * g.x + bb.x;
    nv.y = (v.y - mu) * rs * g.y + bb.y;
    nv.z = (v.z - mu) * rs * g.z + bb.z;
    nv.w = (v.w - mu) * rs * g.w + bb.w;
    s4v o;
    o[0] = f2bf(nv.x); o[1] = f2bf(nv.y); o[2] = f2bf(nv.z); o[3] = f2bf(nv.w);
    ob[c] = o;
    if (outf) of[c] = nv;
  }
}

__global__ __launch_bounds__(256) void copy_out(const float* __restrict__ x,
                                                float* __restrict__ out, size_t n4) {
  size_t i = (size_t)blockIdx.x * 256 + threadIdx.x;
  size_t stride = (size_t)gridDim.x * 256;
  const float4* xi = (const float4*)x;
  float4* oi = (float4*)out;
  for (; i < n4; i += stride) oi[i] = xi[i];
}

__global__ __launch_bounds__(256) void scatter_add(const int* __restrict__ idx,
                                                   const float* __restrict__ cur,
                                                   float* out) {
  int r = blockIdx.x;
  int b = r >> 10, kk = r & (KK - 1);
  int dst = idx[b * KK + kk];
  float4* o = (float4*)(out + ((size_t)b * SS + dst) * HH);
  const float4* c = (const float4*)(cur + (size_t)r * HH);
  int t = threadIdx.x;
#pragma unroll
  for (int i = 0; i < 2; ++i) {
    int j = t + i * 256;
    float4 ov = o[j], cv = c[j];
    ov.x += cv.x; ov.y += cv.y; ov.z += cv.z; ov.w += cv.w;
    o[j] = ov;
  }
}

extern "C" void kernel_launch(void* const* d_in, const int* in_sizes, int n_in,
                              void* d_out, int out_size, void* d_ws, size_t ws_size,
                              hipStream_t stream) {
  (void)in_sizes; (void)n_in; (void)out_size; (void)ws_size;
  const float* x = (const float*)d_in[0];
  const float* prv = (const float*)d_in[1];
  const int* idx = (const int*)d_in[2];
  const float* Wq = (const float*)d_in[3];
  const float* Wk = (const float*)d_in[4];
  const float* Wv = (const float*)d_in[5];
  const float* Wo = (const float*)d_in[6];
  const float* ag = (const float*)d_in[7];
  const float* ab = (const float*)d_in[8];
  const float* mg = (const float*)d_in[9];
  const float* mbt = (const float*)d_in[10];
  const float* Wg = (const float*)d_in[11];
  const float* Wu = (const float*)d_in[12];
  const float* Wd = (const float*)d_in[13];
  float* out = (float*)d_out;

  char* ws = (char*)d_ws;
  size_t off = 0;
  auto alloc = [&](size_t bytes) -> void* {
    void* p = ws + off;
    off += (bytes + 255) & ~(size_t)255;
    return p;
  };
  const size_t WHH = (size_t)HH * HH, WHF = (size_t)HH * FFF;
  short* WqT = (short*)alloc(LL * WHH * 2);
  short* WkvT = (short*)alloc(LL * 2 * WHH * 2);   // [l][K rows | V rows][HH]
  short* WoT = (short*)alloc(LL * WHH * 2);
  short* WguT = (short*)alloc(LL * 2 * WHF * 2);   // [l][interleaved gate|up][HH]
  short* WdT = (short*)alloc(LL * WHF * 2);
  const size_t RH = (size_t)BB * KK * HH;
  float* cur_f = (float*)alloc(RH * 4);
  short* q_b = (short*)alloc(RH * 2);
  short* k_b = (short*)alloc(RH * 2);
  short* vT_b = (short*)alloc(RH * 2);
  short* o_b = (short*)alloc(RH * 2);
  short* cur_b = (short*)alloc(RH * 2);
  short* mem_b = (short*)alloc(RH * 2);
  short* nrm_b = (short*)alloc(RH * 2);
  short* hid_b = vT_b;  // 32MB alias over vT_b+o_b region (dead during MLP)

  dim3 blk(256), blk512(512);
  for (int l = 0; l < LL; ++l) {
    wconv<<<dim3(HH / 64, HH / 64), blk, 0, stream>>>(Wq + l * WHH, WqT + l * WHH, HH, HH, 0);
    wconv<<<dim3(HH / 64, HH / 64), blk, 0, stream>>>(Wk + l * WHH, WkvT + l * 2 * WHH, HH, HH, 0);
    wconv<<<dim3(HH / 64, HH / 64), blk, 0, stream>>>(Wv + l * WHH, WkvT + l * 2 * WHH + WHH, HH, HH, 0);
    wconv<<<dim3(HH / 64, HH / 64), blk, 0, stream>>>(Wo + l * WHH, WoT + l * WHH, HH, HH, 0);
    wconv<<<dim3(FFF / 64, HH / 64), blk, 0, stream>>>(Wg + l * WHF, WguT + l * 2 * WHF, HH, FFF, 1);
    wconv<<<dim3(FFF / 64, HH / 64), blk, 0, stream>>>(Wu + l * WHF, WguT + l * 2 * WHF, HH, FFF, 2);
    wconv<<<dim3(HH / 64, FFF / 64), blk, 0, stream>>>(Wd + l * WHF, WdT + l * WHF, FFF, HH, 0);
  }
  gather_rows<<<dim3(BB * KK), blk, 0, stream>>>(x, prv, idx, cur_f, cur_b, mem_b);

  const int M = BB * KK;
  for (int l = 0; l < LL; ++l) {
    const short* wq = WqT + l * WHH;
    const short* wkv = WkvT + l * 2 * WHH;
    const short* wo = WoT + l * WHH;
    const short* wgu = WguT + l * 2 * WHF;
    const short* wd = WdT + l * WHF;
    g8p<0><<<dim3(HH / 256, M / 128), blk512, 0, stream>>>(cur_b, wq, nullptr, q_b, M, HH, HH);
    g256<5><<<dim3(2 * HH / 256, M / 256), blk512, 0, stream>>>(mem_b, wkv, k_b, vT_b, M, 2 * HH, HH);
    attn_fwd<<<dim3(KK / 64, NHH, BB), blk, 0, stream>>>(q_b, k_b, vT_b, o_b);
    g8p<1><<<dim3(HH / 256, M / 128), blk512, 0, stream>>>(o_b, wo, cur_f, nullptr, M, HH, HH);
    ln_rows<<<dim3(M), blk, 0, stream>>>(cur_f, ag + l * HH, ab + l * HH, nrm_b, nullptr);
    g256<7><<<dim3(2 * FFF / 256, M / 256), blk512, 0, stream>>>(nrm_b, wgu, hid_b, nullptr, M, 2 * FFF, HH);
    g8p<1><<<dim3(HH / 256, M / 128), blk512, 0, stream>>>(hid_b, wd, cur_f, nullptr, M, HH, FFF);
    ln_rows<<<dim3(M), blk, 0, stream>>>(cur_f, mg + l * HH, mbt + l * HH, cur_b, cur_f);
  }
  copy_out<<<dim3(2048), blk, 0, stream>>>(x, out, (size_t)BB * SS * HH / 4);
  scatter_add<<<dim3(M), blk, 0, stream>>>(idx, cur_f, out);
}

// Round 14
// 1246.910 us; speedup vs baseline: 1.0576x; 1.0576x over previous
//
#include <hip/hip_runtime.h>
#include <hip/hip_bf16.h>

#define BB 4
#define SS 2048
#define HH 2048
#define KK 1024
#define LL 2
#define NHH 16
#define FFF 4096
#define DD 128

typedef __attribute__((ext_vector_type(8))) short s8v;
typedef __attribute__((ext_vector_type(4))) short s4v;
typedef __attribute__((ext_vector_type(4))) float f4v;

__device__ __forceinline__ short f2bf(float f) {
  unsigned u = __builtin_bit_cast(unsigned, f);
  u += 0x7fffu + ((u >> 16) & 1u);   // RNE
  return (short)(u >> 16);
}
__device__ __forceinline__ float bf2f(short s) {
  unsigned u = ((unsigned)(unsigned short)s) << 16;
  return __builtin_bit_cast(float, u);
}
__device__ __forceinline__ f4v mfma16(s8v a, s8v b, f4v c) {
  asm("v_mfma_f32_16x16x32_bf16 %0, %1, %2, %0" : "+v"(c) : "v"(a), "v"(b));
  return c;
}
__device__ __forceinline__ void gload_lds16(const void* g, void* l) {
  __builtin_amdgcn_global_load_lds(
      (__attribute__((address_space(1))) void*)g,
      (__attribute__((address_space(3))) void*)l, 16, 0, 0);
}
// Counted-vmcnt barrier: drains expcnt+lgkm fully (expcnt tracks the LDS-write
// half of global_load_lds on gfx950) leaving newest prefetch stage in flight.
template <int N>
__device__ __forceinline__ void barrier_cnt() {
  if constexpr (N == 3)
    asm volatile("s_waitcnt vmcnt(3) expcnt(0) lgkmcnt(0)" ::: "memory");
  else if constexpr (N == 4)
    asm volatile("s_waitcnt vmcnt(4) expcnt(0) lgkmcnt(0)" ::: "memory");
  else
    asm volatile("s_waitcnt vmcnt(0) expcnt(0) lgkmcnt(0)" ::: "memory");
  __builtin_amdgcn_s_barrier();
  asm volatile("" ::: "memory");
}

// ---- weight transpose+convert: W[Kd][N] f32 -> Wt[map(n)][Kd] bf16 ----
// rowmap 0: identity. 1: gate-interleave  n -> 2*(n&~15) + (n&15)
//          2: up-interleave    n -> 2*(n&~15) + 16 + (n&15)
__global__ __launch_bounds__(256) void wconv(const float* __restrict__ W,
                                             short* __restrict__ Wt,
                                             int Kd, int N, int rowmap) {
  __shared__ short tile[64][65];
  int n0 = blockIdx.x * 64, k0 = blockIdx.y * 64;
  int t = threadIdx.x;
#pragma unroll
  for (int i = 0; i < 16; ++i) {
    int lin = i * 256 + t;
    int r = lin >> 6, c = lin & 63;
    tile[c][r] = f2bf(W[(size_t)(k0 + r) * N + n0 + c]);
  }
  __syncthreads();
#pragma unroll
  for (int i = 0; i < 16; ++i) {
    int lin = i * 256 + t;
    int r = lin >> 6, c = lin & 63;
    int n = n0 + r;
    int nf = (rowmap == 0) ? n : (((n & ~15) << 1) + (n & 15) + (rowmap == 2 ? 16 : 0));
    Wt[(size_t)nf * Kd + k0 + c] = tile[r][c];
  }
}

// ---- gather selected rows; produce cur_f32, cur_bf16, mem_bf16 ----
__global__ __launch_bounds__(256) void gather_rows(
    const float* __restrict__ x, const float* __restrict__ prev,
    const int* __restrict__ idx, float* __restrict__ cur_f,
    short* __restrict__ cur_b, short* __restrict__ mem_b) {
  int r = blockIdx.x;
  int b = r >> 10, kk = r & (KK - 1);
  int src = idx[b * KK + kk];
  const float4* xs = (const float4*)(x + ((size_t)b * SS + src) * HH);
  const float4* ps = (const float4*)(prev + ((size_t)b * SS + src) * HH);
  float4* cf = (float4*)(cur_f + (size_t)r * HH);
  s4v* cb = (s4v*)(cur_b + (size_t)r * HH);
  s4v* mb = (s4v*)(mem_b + (size_t)r * HH);
  int t = threadIdx.x;
#pragma unroll
  for (int i = 0; i < 2; ++i) {
    int c = t + i * 256;
    float4 xv = xs[c], pv = ps[c];
    cf[c] = xv;
    s4v cv, mv;
    cv[0] = f2bf(xv.x); cv[1] = f2bf(xv.y); cv[2] = f2bf(xv.z); cv[3] = f2bf(xv.w);
    mv[0] = f2bf(pv.x); mv[1] = f2bf(pv.y); mv[2] = f2bf(pv.z); mv[3] = f2bf(pv.w);
    cb[c] = cv; mb[c] = mv;
  }
}

// ==== g8p: 8-wave 128x256, waves 64x64; 3-buffer counted-vmcnt + T2 ====
// (R12-verified single-phase loop)
// EPI: 0=bf16, 1=f32 +=, 2=V-transpose bf16
template <int EPI>
__global__ __launch_bounds__(512, 2) void g8p(
    const short* __restrict__ A, const short* __restrict__ Bt,
    float* __restrict__ Cf, short* __restrict__ Cb,
    int M, int N, int Kd) {
  __shared__ __align__(16) short smem[3 * 12288];
  const int t = threadIdx.x;
  const int w = t >> 6, l = t & 63;
  const int wr = w >> 2, wc = w & 3;            // 2(M) x 4(N) waves
  const int l15 = l & 15, lh = l >> 4;
  const int koffs = (lh ^ ((l15 >> 1) & 3)) * 8;

  const int gx = gridDim.x, gy = gridDim.y;
  const int nwg = gx * gy;
  const int bid = blockIdx.y * gx + blockIdx.x;
  const int wg = (bid & 7) * (nwg >> 3) + (bid >> 3);
  const int by = wg & (gy - 1);
  const int bx = wg / gy;
  const int rowBase = by * 128, colBase = bx * 256;

  const int ar = t >> 2;
  const int ac = ((t & 3) ^ ((t >> 3) & 3)) * 8;
  const short* gA = A + (size_t)(rowBase + ar) * Kd + ac;
  const short* gB0 = Bt + (size_t)(colBase + ar) * Kd + ac;
  const short* gB1 = gB0 + (size_t)128 * Kd;
  const int lA = t * 8;
  const int lB = 4096 + t * 8;

  auto stage = [&](int bi, int kt) {
    const int k0 = kt * 32;
    short* base = smem + bi * 12288;
    gload_lds16(gA + k0, base + lA);
    gload_lds16(gB0 + k0, base + lB);
    gload_lds16(gB1 + k0, base + lB + 4096);
  };

  f4v acc[4][4];
#pragma unroll
  for (int i = 0; i < 4; ++i)
#pragma unroll
    for (int j = 0; j < 4; ++j) acc[i][j] = (f4v){0.f, 0.f, 0.f, 0.f};

  const int NT = Kd >> 5;
  stage(0, 0);
  stage(1, 1);
  barrier_cnt<3>();

  int cur = 0;
  for (int kt = 0; kt < NT; ++kt) {
    const short* sb = smem + cur * 12288;
    const bool more = (kt + 2 < NT);
    if (more) {
      int nb = cur + 2; if (nb >= 3) nb -= 3;
      stage(nb, kt + 2);
    }
    s8v af[4], bf[4];
#pragma unroll
    for (int mt = 0; mt < 4; ++mt)
      af[mt] = *(const s8v*)(sb + (wr * 64 + mt * 16 + l15) * 32 + koffs);
#pragma unroll
    for (int nt = 0; nt < 4; ++nt)
      bf[nt] = *(const s8v*)(sb + 4096 + (wc * 64 + nt * 16 + l15) * 32 + koffs);
#pragma unroll
    for (int mt = 0; mt < 4; ++mt)
#pragma unroll
      for (int nt = 0; nt < 4; ++nt)
        acc[mt][nt] = mfma16(af[mt], bf[nt], acc[mt][nt]);
    if (more) barrier_cnt<3>(); else barrier_cnt<0>();
    cur = (cur + 1 == 3) ? 0 : cur + 1;
  }

#pragma unroll
  for (int mt = 0; mt < 4; ++mt) {
#pragma unroll
    for (int nt = 0; nt < 4; ++nt) {
#pragma unroll
      for (int rr = 0; rr < 4; ++rr) {
        int row = rowBase + wr * 64 + mt * 16 + lh * 4 + rr;
        int col = colBase + wc * 64 + nt * 16 + l15;
        float v = acc[mt][nt][rr];
        if constexpr (EPI == 0) {
          Cb[(size_t)row * N + col] = f2bf(v);
        } else if constexpr (EPI == 1) {
          Cf[(size_t)row * N + col] += v;
        } else if constexpr (EPI == 2) {
          int b = row >> 10, ktok = row & (KK - 1);
          int h = col >> 7, dd = col & (DD - 1);
          Cb[(((size_t)(b * NHH + h)) * DD + dd) * KK + ktok] = f2bf(v);
        }
      }
    }
  }
}

// ==== g256: 256x256 tile, 8 waves of 64x128 (R12-verified loop) ====
// EPI 5: fused K|V; EPI 7: interleaved gate|up with in-register SwiGLU
template <int EPI>
__global__ __launch_bounds__(512, 2) void g256(
    const short* __restrict__ A, const short* __restrict__ Bt,
    short* __restrict__ Cb, short* __restrict__ Cb2, int M, int N, int Kd) {
  __shared__ __align__(16) short smem[3 * 16384];
  const int t = threadIdx.x;
  const int w = t >> 6, l = t & 63;
  const int wr = w >> 1, wc = w & 1;            // 4(M) x 2(N) waves
  const int l15 = l & 15, lh = l >> 4;
  const int koffs = (lh ^ ((l15 >> 1) & 3)) * 8;

  const int gx = gridDim.x, gy = gridDim.y;
  const int nwg = gx * gy;
  const int bid = blockIdx.y * gx + blockIdx.x;
  const int wg = (bid & 7) * (nwg >> 3) + (bid >> 3);
  const int by = wg & (gy - 1);
  const int bx = wg / gy;
  const int rowBase = by * 256, colBase = bx * 256;

  const int ar = t >> 2;
  const int ac = ((t & 3) ^ ((t >> 3) & 3)) * 8;
  const short* gA = A + (size_t)(rowBase + ar) * Kd + ac;
  const short* gB = Bt + (size_t)(colBase + ar) * Kd + ac;
  const int lA = t * 8;
  const int lB = 8192 + t * 8;

  auto stage = [&](int bi, int kt) {
    const int k0 = kt * 32;
    short* base = smem + bi * 16384;
    gload_lds16(gA + k0, base + lA);
    gload_lds16(gA + k0 + (size_t)128 * Kd, base + lA + 4096);
    gload_lds16(gB + k0, base + lB);
    gload_lds16(gB + k0 + (size_t)128 * Kd, base + lB + 4096);
  };

  f4v acc[4][8];
#pragma unroll
  for (int i = 0; i < 4; ++i)
#pragma unroll
    for (int j = 0; j < 8; ++j) acc[i][j] = (f4v){0.f, 0.f, 0.f, 0.f};

  const int NT = Kd >> 5;
  stage(0, 0);
  stage(1, 1);
  barrier_cnt<4>();

  int cur = 0;
  for (int kt = 0; kt < NT; ++kt) {
    const short* sb = smem + cur * 16384;
    const bool more = (kt + 2 < NT);
    if (more) {
      int nb = cur + 2; if (nb >= 3) nb -= 3;
      stage(nb, kt + 2);
    }
    s8v af[4], bf[8];
#pragma unroll
    for (int mt = 0; mt < 4; ++mt)
      af[mt] = *(const s8v*)(sb + (wr * 64 + mt * 16 + l15) * 32 + koffs);
#pragma unroll
    for (int nt = 0; nt < 8; ++nt)
      bf[nt] = *(const s8v*)(sb + 8192 + (wc * 128 + nt * 16 + l15) * 32 + koffs);
#pragma unroll
    for (int mt = 0; mt < 4; ++mt)
#pragma unroll
      for (int nt = 0; nt < 8; ++nt)
        acc[mt][nt] = mfma16(af[mt], bf[nt], acc[mt][nt]);
    if (more) barrier_cnt<4>(); else barrier_cnt<0>();
    cur = (cur + 1 == 3) ? 0 : cur + 1;
  }

#pragma unroll
  for (int mt = 0; mt < 4; ++mt) {
    if constexpr (EPI == 5) {
#pragma unroll
      for (int nt = 0; nt < 8; ++nt) {
#pragma unroll
        for (int rr = 0; rr < 4; ++rr) {
          int row = rowBase + wr * 64 + mt * 16 + lh * 4 + rr;
          int col = colBase + wc * 128 + nt * 16 + l15;
          float v = acc[mt][nt][rr];
          if (col < HH) {
            Cb[(size_t)row * HH + col] = f2bf(v);
          } else {
            int vcol = col - HH;
            int b = row >> 10, ktok = row & (KK - 1);
            int h = vcol >> 7, dd = vcol & (DD - 1);
            Cb2[(((size_t)(b * NHH + h)) * DD + dd) * KK + ktok] = f2bf(v);
          }
        }
      }
    } else {   // EPI 7: in-register SwiGLU; nt even = gate, nt+1 = up (same j)
#pragma unroll
      for (int nt = 0; nt < 8; nt += 2) {
#pragma unroll
        for (int rr = 0; rr < 4; ++rr) {
          int row = rowBase + wr * 64 + mt * 16 + lh * 4 + rr;
          int c = colBase + wc * 128 + nt * 16 + l15;
          int j = ((c >> 5) << 4) | (c & 15);
          float g = acc[mt][nt][rr];
          float u = acc[mt][nt + 1][rr];
          float h = (g / (1.f + __expf(-g))) * u;
          Cb[(size_t)row * FFF + j] = f2bf(h);
        }
      }
    }
  }
}

// ---- fused attention: log2-space softmax + T14 async-STAGE split ----
__device__ __forceinline__ float exp2fast(float x) {
  float r;
  asm("v_exp_f32 %0, %1\n\ts_nop 0" : "=v"(r) : "v"(x));
  return r;
}
__global__ __launch_bounds__(256, 2) void attn_fwd(
    const short* __restrict__ qb, const short* __restrict__ kb,
    const short* __restrict__ vT, short* __restrict__ ob) {
  __shared__ __align__(16) short Kl[64 * 136];
  __shared__ __align__(16) short Vl[128 * 72];
  __shared__ __align__(16) short Pl[64 * 72];
  int b = blockIdx.z, h = blockIdx.y, qt = blockIdx.x;
  int t = threadIdx.x, w = t >> 6, l = t & 63, l15 = l & 15, lh = l >> 4;
  const float LOG2E = 1.4426950408889634f;
  float slope2 = exp2f(-0.5f * (float)(h + 1)) * LOG2E;
  const float c1 = 0.08838834764831845f * LOG2E;

  s8v qf[4];
  int qrowA = qt * 64 + w * 16 + l15;
  const short* qptr = qb + ((size_t)(b * KK + qrowA)) * HH + h * DD + lh * 8;
#pragma unroll
  for (int ks = 0; ks < 4; ++ks) qf[ks] = *(const s8v*)(qptr + ks * 32);

  // T14: per-thread K/V staging slots; loads issued a tile early, writes late
  const int krr = t >> 4, kcc = (t & 15) * 8;
  const int vdr = t >> 3, vc2 = (t & 7) * 8;
  s8v kreg[4], vreg[4];
  auto loadKV = [&](int kt) {
#pragma unroll
    for (int it = 0; it < 4; ++it)
      kreg[it] = *(const s8v*)(kb + ((size_t)(b * KK + kt * 64 + it * 16 + krr)) * HH + h * DD + kcc);
#pragma unroll
    for (int it = 0; it < 4; ++it)
      vreg[it] = *(const s8v*)(vT + (((size_t)(b * NHH + h)) * DD + it * 32 + vdr) * KK + kt * 64 + vc2);
  };

  f4v oacc[8];
#pragma unroll
  for (int i = 0; i < 8; ++i) oacc[i] = (f4v){0.f, 0.f, 0.f, 0.f};
  float m[4], sden[4];
#pragma unroll
  for (int r = 0; r < 4; ++r) { m[r] = -1e30f; sden[r] = 0.f; }
  int qpos_base = qt * 64 + w * 16 + lh * 4;

  loadKV(0);
  for (int kt = 0; kt < KK / 64; ++kt) {
    // LDS free here (first iter or tail barrier of previous iter)
#pragma unroll
    for (int it = 0; it < 4; ++it)
      *(s8v*)&Kl[(it * 16 + krr) * 136 + kcc] = kreg[it];
#pragma unroll
    for (int it = 0; it < 4; ++it)
      *(s8v*)&Vl[(it * 32 + vdr) * 72 + vc2] = vreg[it];
    __syncthreads();
    // issue next tile's global loads now -- latency hides under compute below
    if (kt + 1 < KK / 64) loadKV(kt + 1);

    f4v sacc[4];
#pragma unroll
    for (int ct = 0; ct < 4; ++ct) sacc[ct] = (f4v){0.f, 0.f, 0.f, 0.f};
#pragma unroll
    for (int ct = 0; ct < 4; ++ct)
#pragma unroll
      for (int ks = 0; ks < 4; ++ks) {
        s8v kf = *(const s8v*)&Kl[(ct * 16 + l15) * 136 + ks * 32 + lh * 8];
        sacc[ct] = mfma16(qf[ks], kf, sacc[ct]);
      }

#pragma unroll
    for (int r = 0; r < 4; ++r) {
      int qpos = qpos_base + r;
      float mx = -1e30f;
#pragma unroll
      for (int ct = 0; ct < 4; ++ct) {
        int kpos = kt * 64 + ct * 16 + l15;
        float sv = sacc[ct][r] * c1 - slope2 * fabsf((float)(qpos - kpos));
        sacc[ct][r] = sv;
        mx = fmaxf(mx, sv);
      }
      mx = fmaxf(mx, __shfl_xor(mx, 1));
      mx = fmaxf(mx, __shfl_xor(mx, 2));
      mx = fmaxf(mx, __shfl_xor(mx, 4));
      mx = fmaxf(mx, __shfl_xor(mx, 8));
      float mn = fmaxf(m[r], mx);
      float corr = exp2fast(m[r] - mn);
      m[r] = mn;
      float ps = 0.f;
#pragma unroll
      for (int ct = 0; ct < 4; ++ct) {
        float p = exp2fast(sacc[ct][r] - mn);
        sacc[ct][r] = p;
        ps += p;
      }
      ps += __shfl_xor(ps, 1); ps += __shfl_xor(ps, 2);
      ps += __shfl_xor(ps, 4); ps += __shfl_xor(ps, 8);
      sden[r] = sden[r] * corr + ps;
#pragma unroll
      for (int dt = 0; dt < 8; ++dt) oacc[dt][r] *= corr;
#pragma unroll
      for (int ct = 0; ct < 4; ++ct)
        Pl[(w * 16 + lh * 4 + r) * 72 + ct * 16 + l15] = f2bf(sacc[ct][r]);
    }

#pragma unroll
    for (int ks2 = 0; ks2 < 2; ++ks2) {
      s8v pa = *(const s8v*)&Pl[(w * 16 + l15) * 72 + ks2 * 32 + lh * 8];
#pragma unroll
      for (int dt = 0; dt < 8; ++dt) {
        s8v vf = *(const s8v*)&Vl[(dt * 16 + l15) * 72 + ks2 * 32 + lh * 8];
        oacc[dt] = mfma16(pa, vf, oacc[dt]);
      }
    }
    __syncthreads();   // all LDS reads done -> free for next tile's writes
  }

#pragma unroll
  for (int dt = 0; dt < 8; ++dt)
#pragma unroll
    for (int r = 0; r < 4; ++r) {
      int qpos = qpos_base + r;
      int dd = dt * 16 + l15;
      ob[((size_t)(b * KK + qpos)) * HH + h * DD + dd] = f2bf(oacc[dt][r] / sden[r]);
    }
}

// ---- LayerNorm over rows of HH; writes bf16 (+ optional f32 in-place) ----
__global__ __launch_bounds__(256) void ln_rows(const float* in,
    const float* __restrict__ gma, const float* __restrict__ bta,
    short* __restrict__ outb, float* outf) {
  __shared__ float red[2][4];
  int r = blockIdx.x, t = threadIdx.x;
  const float4* x4 = (const float4*)(in + (size_t)r * HH);
  float4 va = x4[t], vb = x4[t + 256];
  float sum = va.x + va.y + va.z + va.w + vb.x + vb.y + vb.z + vb.w;
  float sq = va.x * va.x + va.y * va.y + va.z * va.z + va.w * va.w +
             vb.x * vb.x + vb.y * vb.y + vb.z * vb.z + vb.w * vb.w;
#pragma unroll
  for (int off = 32; off; off >>= 1) {
    sum += __shfl_down(sum, off);
    sq += __shfl_down(sq, off);
  }
  int w = t >> 6;
  if ((t & 63) == 0) { red[0][w] = sum; red[1][w] = sq; }
  __syncthreads();
  sum = red[0][0] + red[0][1] + red[0][2] + red[0][3];
  sq = red[1][0] + red[1][1] + red[1][2] + red[1][3];
  float mu = sum * (1.f / HH);
  float rs = rsqrtf(sq * (1.f / HH) - mu * mu + 1e-5f);
  const float4* g4 = (const float4*)gma;
  const float4* b4 = (const float4*)bta;
  s4v* ob = (s4v*)(outb + (size_t)r * HH);
  float4* of = (float4*)(outf ? outf + (size_t)r * HH : nullptr);
#pragma unroll
  for (int i = 0; i < 2; ++i) {
    int c = t + i * 256;
    float4 v = (i == 0) ? va : vb;
    float4 g = g4[c], bb = b4[c];
    float4 nv;
    nv.x = (v.x - mu) * rs * g.x + bb.x;
    nv.y = (v.y - mu) * rs * g.y + bb.y;
    nv.z = (v.z - mu) * rs * g.z + bb.z;
    nv.w = (v.w - mu) * rs * g.w + bb.w;
    s4v o;
    o[0] = f2bf(nv.x); o[1] = f2bf(nv.y); o[2] = f2bf(nv.z); o[3] = f2bf(nv.w);
    ob[c] = o;
    if (outf) of[c] = nv;
  }
}

__global__ __launch_bounds__(256) void copy_out(const float* __restrict__ x,
                                                float* __restrict__ out, size_t n4) {
  size_t i = (size_t)blockIdx.x * 256 + threadIdx.x;
  size_t stride = (size_t)gridDim.x * 256;
  const float4* xi = (const float4*)x;
  float4* oi = (float4*)out;
  for (; i < n4; i += stride) oi[i] = xi[i];
}

__global__ __launch_bounds__(256) void scatter_add(const int* __restrict__ idx,
                                                   const float* __restrict__ cur,
                                                   float* out) {
  int r = blockIdx.x;
  int b = r >> 10, kk = r & (KK - 1);
  int dst = idx[b * KK + kk];
  float4* o = (float4*)(out + ((size_t)b * SS + dst) * HH);
  const float4* c = (const float4*)(cur + (size_t)r * HH);
  int t = threadIdx.x;
#pragma unroll
  for (int i = 0; i < 2; ++i) {
    int j = t + i * 256;
    float4 ov = o[j], cv = c[j];
    ov.x += cv.x; ov.y += cv.y; ov.z += cv.z; ov.w += cv.w;
    o[j] = ov;
  }
}

extern "C" void kernel_launch(void* const* d_in, const int* in_sizes, int n_in,
                              void* d_out, int out_size, void* d_ws, size_t ws_size,
                              hipStream_t stream) {
  (void)in_sizes; (void)n_in; (void)out_size; (void)ws_size;
  const float* x = (const float*)d_in[0];
  const float* prv = (const float*)d_in[1];
  const int* idx = (const int*)d_in[2];
  const float* Wq = (const float*)d_in[3];
  const float* Wk = (const float*)d_in[4];
  const float* Wv = (const float*)d_in[5];
  const float* Wo = (const float*)d_in[6];
  const float* ag = (const float*)d_in[7];
  const float* ab = (const float*)d_in[8];
  const float* mg = (const float*)d_in[9];
  const float* mbt = (const float*)d_in[10];
  const float* Wg = (const float*)d_in[11];
  const float* Wu = (const float*)d_in[12];
  const float* Wd = (const float*)d_in[13];
  float* out = (float*)d_out;

  char* ws = (char*)d_ws;
  size_t off = 0;
  auto alloc = [&](size_t bytes) -> void* {
    void* p = ws + off;
    off += (bytes + 255) & ~(size_t)255;
    return p;
  };
  const size_t WHH = (size_t)HH * HH, WHF = (size_t)HH * FFF;
  short* WqT = (short*)alloc(LL * WHH * 2);
  short* WkvT = (short*)alloc(LL * 2 * WHH * 2);   // [l][K rows | V rows][HH]
  short* WoT = (short*)alloc(LL * WHH * 2);
  short* WguT = (short*)alloc(LL * 2 * WHF * 2);   // [l][interleaved gate|up][HH]
  short* WdT = (short*)alloc(LL * WHF * 2);
  const size_t RH = (size_t)BB * KK * HH;
  float* cur_f = (float*)alloc(RH * 4);
  short* q_b = (short*)alloc(RH * 2);
  short* k_b = (short*)alloc(RH * 2);
  short* vT_b = (short*)alloc(RH * 2);
  short* o_b = (short*)alloc(RH * 2);
  short* cur_b = (short*)alloc(RH * 2);
  short* mem_b = (short*)alloc(RH * 2);
  short* nrm_b = (short*)alloc(RH * 2);
  short* hid_b = vT_b;  // 32MB alias over vT_b+o_b region (dead during MLP)

  dim3 blk(256), blk512(512);
  for (int l = 0; l < LL; ++l) {
    wconv<<<dim3(HH / 64, HH / 64), blk, 0, stream>>>(Wq + l * WHH, WqT + l * WHH, HH, HH, 0);
    wconv<<<dim3(HH / 64, HH / 64), blk, 0, stream>>>(Wk + l * WHH, WkvT + l * 2 * WHH, HH, HH, 0);
    wconv<<<dim3(HH / 64, HH / 64), blk, 0, stream>>>(Wv + l * WHH, WkvT + l * 2 * WHH + WHH, HH, HH, 0);
    wconv<<<dim3(HH / 64, HH / 64), blk, 0, stream>>>(Wo + l * WHH, WoT + l * WHH, HH, HH, 0);
    wconv<<<dim3(FFF / 64, HH / 64), blk, 0, stream>>>(Wg + l * WHF, WguT + l * 2 * WHF, HH, FFF, 1);
    wconv<<<dim3(FFF / 64, HH / 64), blk, 0, stream>>>(Wu + l * WHF, WguT + l * 2 * WHF, HH, FFF, 2);
    wconv<<<dim3(HH / 64, FFF / 64), blk, 0, stream>>>(Wd + l * WHF, WdT + l * WHF, FFF, HH, 0);
  }
  gather_rows<<<dim3(BB * KK), blk, 0, stream>>>(x, prv, idx, cur_f, cur_b, mem_b);

  const int M = BB * KK;
  for (int l = 0; l < LL; ++l) {
    const short* wq = WqT + l * WHH;
    const short* wkv = WkvT + l * 2 * WHH;
    const short* wo = WoT + l * WHH;
    const short* wgu = WguT + l * 2 * WHF;
    const short* wd = WdT + l * WHF;
    g8p<0><<<dim3(HH / 256, M / 128), blk512, 0, stream>>>(cur_b, wq, nullptr, q_b, M, HH, HH);
    g256<5><<<dim3(2 * HH / 256, M / 256), blk512, 0, stream>>>(mem_b, wkv, k_b, vT_b, M, 2 * HH, HH);
    attn_fwd<<<dim3(KK / 64, NHH, BB), blk, 0, stream>>>(q_b, k_b, vT_b, o_b);
    g8p<1><<<dim3(HH / 256, M / 128), blk512, 0, stream>>>(o_b, wo, cur_f, nullptr, M, HH, HH);
    ln_rows<<<dim3(M), blk, 0, stream>>>(cur_f, ag + l * HH, ab + l * HH, nrm_b, nullptr);
    g256<7><<<dim3(2 * FFF / 256, M / 256), blk512, 0, stream>>>(nrm_b, wgu, hid_b, nullptr, M, 2 * FFF, HH);
    g8p<1><<<dim3(HH / 256, M / 128), blk512, 0, stream>>>(hid_b, wd, cur_f, nullptr, M, HH, FFF);
    ln_rows<<<dim3(M), blk, 0, stream>>>(cur_f, mg + l * HH, mbt + l * HH, cur_b, cur_f);
  }
  copy_out<<<dim3(2048), blk, 0, stream>>>(x, out, (size_t)BB * SS * HH / 4);
  scatter_add<<<dim3(M), blk, 0, stream>>>(idx, cur_f, out);
}